// Round 1
// baseline (201.678 us; speedup 1.0000x reference)
//
#include <hip/hip_runtime.h>
#include <hip/hip_bf16.h>
#include <cstdint>
#include <cstddef>

// Problem constants (from reference)
#define F0v   2048
#define F1v   2304
#define F2v   2560
#define E1v   256
#define E2v   256
#define BROWS 8192
#define ODIM  1024
#define NNZv  262144
#define NBv   1024

typedef __bf16 bf16x8 __attribute__((ext_vector_type(8)));
typedef float floatx4 __attribute__((ext_vector_type(4)));

__device__ __forceinline__ unsigned short f2bf(float f) {
  unsigned int u = __float_as_uint(f);
  u += 0x7FFFu + ((u >> 16) & 1u);   // round-to-nearest-even
  return (unsigned short)(u >> 16);
}

__device__ __forceinline__ void async_ld16(const void* g, void* l) {
  __builtin_amdgcn_global_load_lds(
      (const __attribute__((address_space(1))) unsigned int*)g,
      (__attribute__((address_space(3))) unsigned int*)l, 16, 0, 0);
}

// ---------------------------------------------------------------------------
// Kernel 1: build h = [x | relu(x[e1p]*e1w) | relu(h[e2p]*e2w)] as bf16
// One 256-thread block per row.
// ---------------------------------------------------------------------------
__global__ __launch_bounds__(256) void build_h_kernel(
    const float* __restrict__ x, const float* __restrict__ e1w,
    const float* __restrict__ e2w, const int* __restrict__ e1p,
    const int* __restrict__ e2p, unsigned short* __restrict__ h) {
  __shared__ float xrow[F0v];
  __shared__ float ytail[E1v + E2v];
  const int b = blockIdx.x;
  const int tid = threadIdx.x;
  const float* xr = x + (size_t)b * F0v;
  unsigned short* hr = h + (size_t)b * F2v;

  float4 v0 = ((const float4*)xr)[tid * 2];
  float4 v1 = ((const float4*)xr)[tid * 2 + 1];
  ((float4*)xrow)[tid * 2] = v0;
  ((float4*)xrow)[tid * 2 + 1] = v1;
  union { unsigned short us[8]; uint4 u4; } pk;
  pk.us[0] = f2bf(v0.x); pk.us[1] = f2bf(v0.y);
  pk.us[2] = f2bf(v0.z); pk.us[3] = f2bf(v0.w);
  pk.us[4] = f2bf(v1.x); pk.us[5] = f2bf(v1.y);
  pk.us[6] = f2bf(v1.z); pk.us[7] = f2bf(v1.w);
  ((uint4*)hr)[tid] = pk.u4;   // cols tid*8 .. tid*8+7
  __syncthreads();

  // layer 1 (E1 = 256 == blockDim)
  float v1l = fmaxf(xrow[e1p[tid]] * e1w[tid], 0.0f);
  ytail[tid] = v1l;
  __syncthreads();

  // layer 2: parent may be in x (col < 2048) or layer-1 output
  int p2 = e2p[tid];
  float hv = (p2 < F0v) ? xrow[p2] : ytail[p2 - F0v];
  float v2l = fmaxf(hv * e2w[tid], 0.0f);
  ytail[E1v + tid] = v2l;
  __syncthreads();

  if (tid < 64) {
    union { unsigned short us[8]; uint4 u4; } pt;
#pragma unroll
    for (int j = 0; j < 8; ++j) pt.us[j] = f2bf(ytail[tid * 8 + j]);
    ((uint4*)(hr + F0v))[tid] = pt.u4;   // cols 2048 .. 2559
  }
}

// ---------------------------------------------------------------------------
// Kernel 2: COO scatter-add into dense f32 W [ODIM][F2] + bias [ODIM]
// ---------------------------------------------------------------------------
__global__ __launch_bounds__(256) void scatter_kernel(
    const int* __restrict__ wr, const int* __restrict__ wc,
    const float* __restrict__ wv, const int* __restrict__ bidx,
    const float* __restrict__ bv, float* __restrict__ Wd,
    float* __restrict__ bias) {
  int gid = blockIdx.x * 256 + threadIdx.x;
  if (gid < NNZv)
    atomicAdd(&Wd[(size_t)wr[gid] * F2v + wc[gid]], wv[gid]);
  if (gid < NBv)
    atomicAdd(&bias[bidx[gid]], bv[gid]);
}

// ---------------------------------------------------------------------------
// Kernel 3: W f32 -> bf16 (8 elems/thread)
// ---------------------------------------------------------------------------
__global__ __launch_bounds__(256) void convert_kernel(
    const float* __restrict__ Wd, unsigned short* __restrict__ Wb) {
  int gid = blockIdx.x * 256 + threadIdx.x;  // 0 .. 327679
  const float4* src = (const float4*)Wd;
  float4 a = src[gid * 2];
  float4 b = src[gid * 2 + 1];
  union { unsigned short us[8]; uint4 u4; } pk;
  pk.us[0] = f2bf(a.x); pk.us[1] = f2bf(a.y);
  pk.us[2] = f2bf(a.z); pk.us[3] = f2bf(a.w);
  pk.us[4] = f2bf(b.x); pk.us[5] = f2bf(b.y);
  pk.us[6] = f2bf(b.z); pk.us[7] = f2bf(b.w);
  ((uint4*)Wb)[gid] = pk.u4;
}

// ---------------------------------------------------------------------------
// Kernel 4: C = h @ W^T + bias.  m97-structure bf16 MFMA GEMM.
// A = h [8192][2560] bf16 row-major, Bw = W [1024][2560] bf16 row-major.
// 128x128 tile, BK=32, 4 waves (2x2), each wave 4x4 16x16x32 MFMAs.
// ---------------------------------------------------------------------------
#define BM 128
#define BN 128
#define BK 32

__global__ __launch_bounds__(256) void gemm_bt_kernel(
    const unsigned short* __restrict__ A,
    const unsigned short* __restrict__ Bw,
    const float* __restrict__ bias,
    float* __restrict__ C) {
  __shared__ unsigned short As[BM * BK];
  __shared__ unsigned short Bs[BN * BK];
  const int tid = threadIdx.x;
  const int wave = tid >> 6;
  const int lane = tid & 63;
  const int m0 = blockIdx.y * BM;
  const int n0 = blockIdx.x * BN;
  const int wm = wave >> 1;       // 0..1  (M half)
  const int wn = wave & 1;        // 0..1  (N half)
  const int quad = lane >> 4;     // 0..3
  const int r16 = lane & 15;

  // Staging: 8 chunks of 16 rows x 32 cols (1024 B) per tile; 2 chunks/wave.
  // Lane i of a chunk covers row i/4, k-segment (i%4)*8. LDS dest is
  // wave-uniform base; HW scatters at base + lane*16B (matches row-major).
  const int c0 = wave * 2;
  const int srow = lane >> 2;
  const int sseg = (lane & 3) * 8;
  const unsigned short* gA0 = A + (size_t)(m0 + c0 * 16 + srow) * F2v + sseg;
  const unsigned short* gA1 = A + (size_t)(m0 + (c0 + 1) * 16 + srow) * F2v + sseg;
  const unsigned short* gB0 = Bw + (size_t)(n0 + c0 * 16 + srow) * F2v + sseg;
  const unsigned short* gB1 = Bw + (size_t)(n0 + (c0 + 1) * 16 + srow) * F2v + sseg;
  unsigned short* lA0 = &As[c0 * 512];
  unsigned short* lA1 = &As[(c0 + 1) * 512];
  unsigned short* lB0 = &Bs[c0 * 512];
  unsigned short* lB1 = &Bs[(c0 + 1) * 512];

  floatx4 acc[4][4];
  floatx4 zz = {0.f, 0.f, 0.f, 0.f};
#pragma unroll
  for (int i = 0; i < 4; ++i)
#pragma unroll
    for (int j = 0; j < 4; ++j) acc[i][j] = zz;

  for (int k0 = 0; k0 < F2v; k0 += BK) {
    async_ld16(gA0 + k0, lA0);
    async_ld16(gA1 + k0, lA1);
    async_ld16(gB0 + k0, lB0);
    async_ld16(gB1 + k0, lB1);
    __syncthreads();   // compiler drains vmcnt before s_barrier

    bf16x8 af[4], bfr[4];
#pragma unroll
    for (int mi = 0; mi < 4; ++mi)
      af[mi] = *(const bf16x8*)&As[(wm * 64 + mi * 16 + r16) * BK + quad * 8];
#pragma unroll
    for (int ni = 0; ni < 4; ++ni)
      bfr[ni] = *(const bf16x8*)&Bs[(wn * 64 + ni * 16 + r16) * BK + quad * 8];
#pragma unroll
    for (int mi = 0; mi < 4; ++mi)
#pragma unroll
      for (int ni = 0; ni < 4; ++ni)
        acc[mi][ni] = __builtin_amdgcn_mfma_f32_16x16x32_bf16(
            af[mi], bfr[ni], acc[mi][ni], 0, 0, 0);
    __syncthreads();
  }

  // Epilogue: C/D layout col = lane&15, row = quad*4 + reg (m89/m91 verified)
#pragma unroll
  for (int ni = 0; ni < 4; ++ni) {
    int col = n0 + wn * 64 + ni * 16 + r16;
    float bc = bias[col];
#pragma unroll
    for (int mi = 0; mi < 4; ++mi) {
      int row = m0 + wm * 64 + mi * 16 + quad * 4;
#pragma unroll
      for (int rg = 0; rg < 4; ++rg)
        C[(size_t)(row + rg) * ODIM + col] = acc[mi][ni][rg] + bc;
    }
  }
}

// ---------------------------------------------------------------------------
extern "C" void kernel_launch(void* const* d_in, const int* in_sizes, int n_in,
                              void* d_out, int out_size, void* d_ws, size_t ws_size,
                              hipStream_t stream) {
  const float* x    = (const float*)d_in[0];
  const float* e1w  = (const float*)d_in[1];
  const float* e2w  = (const float*)d_in[2];
  const float* wv   = (const float*)d_in[3];
  const float* bv   = (const float*)d_in[4];
  const int*   e1p  = (const int*)d_in[5];
  const int*   e2p  = (const int*)d_in[6];
  const int*   wr   = (const int*)d_in[7];
  const int*   wc   = (const int*)d_in[8];
  const int*   bidx = (const int*)d_in[9];
  float* out = (float*)d_out;

  // Workspace carve (total ~57.7 MB)
  char* ws = (char*)d_ws;
  const size_t h_bytes  = (size_t)BROWS * F2v * 2;        // 41,943,040
  const size_t wd_bytes = (size_t)ODIM * F2v * 4;         // 10,485,760
  const size_t b_bytes  = (size_t)ODIM * 4;               // 4,096
  unsigned short* h   = (unsigned short*)ws;
  float* Wd           = (float*)(ws + h_bytes);
  float* bias         = (float*)(ws + h_bytes + wd_bytes);
  unsigned short* Wb  = (unsigned short*)(ws + h_bytes + wd_bytes + b_bytes);

  hipMemsetAsync(Wd, 0, wd_bytes + b_bytes, stream);
  build_h_kernel<<<BROWS, 256, 0, stream>>>(x, e1w, e2w, e1p, e2p, h);
  scatter_kernel<<<NNZv / 256, 256, 0, stream>>>(wr, wc, wv, bidx, bv, Wd, bias);
  convert_kernel<<<(ODIM * F2v / 8) / 256, 256, 0, stream>>>(Wd, Wb);
  gemm_bt_kernel<<<dim3(ODIM / BN, BROWS / BM), 256, 0, stream>>>(h, Wb, bias, out);
}

// Round 2
// 196.910 us; speedup vs baseline: 1.0242x; 1.0242x over previous
//
#include <hip/hip_runtime.h>
#include <hip/hip_bf16.h>
#include <cstdint>
#include <cstddef>

// Problem constants (from reference)
#define F0v   2048
#define F1v   2304
#define F2v   2560
#define E1v   256
#define E2v   256
#define BROWS 8192
#define ODIM  1024
#define NNZv  262144
#define NBv   1024

typedef __bf16 bf16x8 __attribute__((ext_vector_type(8)));
typedef float floatx4 __attribute__((ext_vector_type(4)));

__device__ __forceinline__ unsigned short f2bf(float f) {
  unsigned int u = __float_as_uint(f);
  u += 0x7FFFu + ((u >> 16) & 1u);   // round-to-nearest-even
  return (unsigned short)(u >> 16);
}

__device__ __forceinline__ void async_ld16(const void* g, void* l) {
  __builtin_amdgcn_global_load_lds(
      (const __attribute__((address_space(1))) unsigned int*)g,
      (__attribute__((address_space(3))) unsigned int*)l, 16, 0, 0);
}

// ---------------------------------------------------------------------------
// Kernel 1 (fused): blocks [0,8192) build h rows; blocks [8192,9216) do the
// COO scatter-add. Independent work fused to overlap and save a launch gap.
// ---------------------------------------------------------------------------
__global__ __launch_bounds__(256) void fused_pre_kernel(
    const float* __restrict__ x, const float* __restrict__ e1w,
    const float* __restrict__ e2w, const int* __restrict__ e1p,
    const int* __restrict__ e2p, unsigned short* __restrict__ h,
    const int* __restrict__ wr, const int* __restrict__ wc,
    const float* __restrict__ wv, const int* __restrict__ bidx,
    const float* __restrict__ bv, float* __restrict__ Wd,
    float* __restrict__ bias) {
  __shared__ float xrow[F0v];
  __shared__ float ytail[E1v + E2v];
  const int tid = threadIdx.x;

  if (blockIdx.x >= BROWS) {
    // ---- scatter branch ----
    int gid = (blockIdx.x - BROWS) * 256 + tid;
    if (gid < NNZv)
      atomicAdd(&Wd[(size_t)wr[gid] * F2v + wc[gid]], wv[gid]);
    if (gid < NBv)
      atomicAdd(&bias[bidx[gid]], bv[gid]);
    return;
  }

  // ---- build_h branch ----
  const int b = blockIdx.x;
  const float* xr = x + (size_t)b * F0v;
  unsigned short* hr = h + (size_t)b * F2v;

  float4 v0 = ((const float4*)xr)[tid * 2];
  float4 v1 = ((const float4*)xr)[tid * 2 + 1];
  ((float4*)xrow)[tid * 2] = v0;
  ((float4*)xrow)[tid * 2 + 1] = v1;
  union { unsigned short us[8]; uint4 u4; } pk;
  pk.us[0] = f2bf(v0.x); pk.us[1] = f2bf(v0.y);
  pk.us[2] = f2bf(v0.z); pk.us[3] = f2bf(v0.w);
  pk.us[4] = f2bf(v1.x); pk.us[5] = f2bf(v1.y);
  pk.us[6] = f2bf(v1.z); pk.us[7] = f2bf(v1.w);
  ((uint4*)hr)[tid] = pk.u4;   // cols tid*8 .. tid*8+7
  __syncthreads();

  // layer 1 (E1 = 256 == blockDim)
  float v1l = fmaxf(xrow[e1p[tid]] * e1w[tid], 0.0f);
  ytail[tid] = v1l;
  __syncthreads();

  // layer 2: parent may be in x (col < 2048) or a layer-1 output
  int p2 = e2p[tid];
  float hv = (p2 < F0v) ? xrow[p2] : ytail[p2 - F0v];
  float v2l = fmaxf(hv * e2w[tid], 0.0f);
  ytail[E1v + tid] = v2l;
  __syncthreads();

  if (tid < 64) {
    union { unsigned short us[8]; uint4 u4; } pt;
#pragma unroll
    for (int j = 0; j < 8; ++j) pt.us[j] = f2bf(ytail[tid * 8 + j]);
    ((uint4*)(hr + F0v))[tid] = pt.u4;   // cols 2048 .. 2559
  }
}

// ---------------------------------------------------------------------------
// Kernel 2: W f32 -> bf16 (8 elems/thread)
// ---------------------------------------------------------------------------
__global__ __launch_bounds__(256) void convert_kernel(
    const float* __restrict__ Wd, unsigned short* __restrict__ Wb) {
  int gid = blockIdx.x * 256 + threadIdx.x;  // 0 .. 327679
  const float4* src = (const float4*)Wd;
  float4 a = src[gid * 2];
  float4 b = src[gid * 2 + 1];
  union { unsigned short us[8]; uint4 u4; } pk;
  pk.us[0] = f2bf(a.x); pk.us[1] = f2bf(a.y);
  pk.us[2] = f2bf(a.z); pk.us[3] = f2bf(a.w);
  pk.us[4] = f2bf(b.x); pk.us[5] = f2bf(b.y);
  pk.us[6] = f2bf(b.z); pk.us[7] = f2bf(b.w);
  ((uint4*)Wb)[gid] = pk.u4;
}

// ---------------------------------------------------------------------------
// Kernel 3: C = h @ W^T + bias.  128x128 tile, BK=32, 512 threads (8 waves),
// each wave 4x2 accs of 16x16x32 bf16 MFMA. 16 waves/CU (vs 8 in round 1)
// for latency hiding; XCD swizzle so each XCD's L2 sees A ~5MB + W ~5MB.
// ---------------------------------------------------------------------------
#define BM 128
#define BN 128
#define BK 32

__global__ __launch_bounds__(512) void gemm_bt_kernel(
    const unsigned short* __restrict__ A,
    const unsigned short* __restrict__ Bw,
    const float* __restrict__ bias,
    float* __restrict__ C) {
  __shared__ unsigned short As[BM * BK];
  __shared__ unsigned short Bs[BN * BK];
  const int tid = threadIdx.x;
  const int wave = tid >> 6;      // 0..7
  const int lane = tid & 63;

  // XCD swizzle: grid (8, 64); id%8 = XCD (round-robin heuristic).
  // Map so XCD k owns M-tiles [8k, 8k+8) across all 8 N-tiles:
  // per-XCD working set = A 5MB (unique) + W 5MB (shared across XCDs).
  const int id = blockIdx.y * 8 + blockIdx.x;
  const int ty = (id & 7) * 8 + ((id >> 3) & 7);   // M-tile 0..63
  const int tx = id >> 6;                          // N-tile 0..7
  const int m0 = ty * BM;
  const int n0 = tx * BN;
  const int wm = wave >> 2;       // 0..1  (64-row half)
  const int wn = wave & 3;        // 0..3  (32-col quarter)
  const int quad = lane >> 4;     // 0..3
  const int r16 = lane & 15;

  // Staging: 8 chunks of 16 rows x 32 cols (1 KiB) per operand tile;
  // one A chunk + one B chunk per wave. Lane i covers row i/4, k-seg (i%4)*8.
  const int srow = lane >> 2;
  const int sseg = (lane & 3) * 8;
  const unsigned short* gA = A + (size_t)(m0 + wave * 16 + srow) * F2v + sseg;
  const unsigned short* gB = Bw + (size_t)(n0 + wave * 16 + srow) * F2v + sseg;
  unsigned short* lA = &As[wave * 512];
  unsigned short* lB = &Bs[wave * 512];

  floatx4 acc[4][2];
  floatx4 zz = {0.f, 0.f, 0.f, 0.f};
#pragma unroll
  for (int i = 0; i < 4; ++i)
#pragma unroll
    for (int j = 0; j < 2; ++j) acc[i][j] = zz;

  for (int k0 = 0; k0 < F2v; k0 += BK) {
    async_ld16(gA + k0, lA);
    async_ld16(gB + k0, lB);
    __syncthreads();   // drains vmcnt before s_barrier

    bf16x8 af[4], bfr[2];
#pragma unroll
    for (int mi = 0; mi < 4; ++mi)
      af[mi] = *(const bf16x8*)&As[(wm * 64 + mi * 16 + r16) * BK + quad * 8];
#pragma unroll
    for (int ni = 0; ni < 2; ++ni)
      bfr[ni] = *(const bf16x8*)&Bs[(wn * 32 + ni * 16 + r16) * BK + quad * 8];
#pragma unroll
    for (int mi = 0; mi < 4; ++mi)
#pragma unroll
      for (int ni = 0; ni < 2; ++ni)
        acc[mi][ni] = __builtin_amdgcn_mfma_f32_16x16x32_bf16(
            af[mi], bfr[ni], acc[mi][ni], 0, 0, 0);
    __syncthreads();
  }

  // Epilogue: C/D layout col = lane&15, row = quad*4 + reg (m89/m91 verified)
#pragma unroll
  for (int ni = 0; ni < 2; ++ni) {
    int col = n0 + wn * 32 + ni * 16 + r16;
    float bc = bias[col];
#pragma unroll
    for (int mi = 0; mi < 4; ++mi) {
      int row = m0 + wm * 64 + mi * 16 + quad * 4;
#pragma unroll
      for (int rg = 0; rg < 4; ++rg)
        C[(size_t)(row + rg) * ODIM + col] = acc[mi][ni][rg] + bc;
    }
  }
}

// ---------------------------------------------------------------------------
extern "C" void kernel_launch(void* const* d_in, const int* in_sizes, int n_in,
                              void* d_out, int out_size, void* d_ws, size_t ws_size,
                              hipStream_t stream) {
  const float* x    = (const float*)d_in[0];
  const float* e1w  = (const float*)d_in[1];
  const float* e2w  = (const float*)d_in[2];
  const float* wv   = (const float*)d_in[3];
  const float* bv   = (const float*)d_in[4];
  const int*   e1p  = (const int*)d_in[5];
  const int*   e2p  = (const int*)d_in[6];
  const int*   wr   = (const int*)d_in[7];
  const int*   wc   = (const int*)d_in[8];
  const int*   bidx = (const int*)d_in[9];
  float* out = (float*)d_out;

  // Workspace carve (total ~57.7 MB)
  char* ws = (char*)d_ws;
  const size_t h_bytes  = (size_t)BROWS * F2v * 2;        // 41,943,040
  const size_t wd_bytes = (size_t)ODIM * F2v * 4;         // 10,485,760
  const size_t b_bytes  = (size_t)ODIM * 4;               // 4,096
  unsigned short* h   = (unsigned short*)ws;
  float* Wd           = (float*)(ws + h_bytes);
  float* bias         = (float*)(ws + h_bytes + wd_bytes);
  unsigned short* Wb  = (unsigned short*)(ws + h_bytes + wd_bytes + b_bytes);

  hipMemsetAsync(Wd, 0, wd_bytes + b_bytes, stream);
  fused_pre_kernel<<<BROWS + NNZv / 256, 256, 0, stream>>>(
      x, e1w, e2w, e1p, e2p, h, wr, wc, wv, bidx, bv, Wd, bias);
  convert_kernel<<<(ODIM * F2v / 8) / 256, 256, 0, stream>>>(Wd, Wb);
  gemm_bt_kernel<<<dim3(ODIM / BN, BROWS / BM), 512, 0, stream>>>(h, Wb, bias, out);
}

// Round 3
// 185.654 us; speedup vs baseline: 1.0863x; 1.0606x over previous
//
#include <hip/hip_runtime.h>
#include <hip/hip_bf16.h>
#include <cstdint>
#include <cstddef>

// Problem constants (from reference)
#define F0v   2048
#define F1v   2304
#define F2v   2560
#define E1v   256
#define E2v   256
#define BROWS 8192
#define ODIM  1024
#define NNZv  262144
#define NBv   1024

typedef __bf16 bf16x8 __attribute__((ext_vector_type(8)));
typedef float floatx4 __attribute__((ext_vector_type(4)));

__device__ __forceinline__ unsigned short f2bf(float f) {
  unsigned int u = __float_as_uint(f);
  u += 0x7FFFu + ((u >> 16) & 1u);   // round-to-nearest-even
  return (unsigned short)(u >> 16);
}

__device__ __forceinline__ void async_ld16(const void* g, void* l) {
  __builtin_amdgcn_global_load_lds(
      (const __attribute__((address_space(1))) unsigned int*)g,
      (__attribute__((address_space(3))) unsigned int*)l, 16, 0, 0);
}

// ---------------------------------------------------------------------------
// Kernel 1 (fused): blocks [0,8192) build h rows (ONE barrier, closed-form
// two-hop tails); blocks [8192,9216) do the COO scatter-add.
// Tail col j == relu(relu(x[src]*wa)*wb); wb=1 encodes single-hop exactly.
// ---------------------------------------------------------------------------
__global__ __launch_bounds__(256) void fused_pre_kernel(
    const float* __restrict__ x, const float* __restrict__ e1w,
    const float* __restrict__ e2w, const int* __restrict__ e1p,
    const int* __restrict__ e2p, unsigned short* __restrict__ h,
    const int* __restrict__ wr, const int* __restrict__ wc,
    const float* __restrict__ wv, const int* __restrict__ bidx,
    const float* __restrict__ bv, float* __restrict__ Wd,
    float* __restrict__ bias) {
  __shared__ float xrow[F0v];
  __shared__ int   tsrc[E1v + E2v];
  __shared__ float twa[E1v + E2v];
  __shared__ float twb[E1v + E2v];
  const int tid = threadIdx.x;

  if (blockIdx.x >= BROWS) {
    // ---- scatter branch ----
    int gid = (blockIdx.x - BROWS) * 256 + tid;
    if (gid < NNZv)
      atomicAdd(&Wd[(size_t)wr[gid] * F2v + wc[gid]], wv[gid]);
    if (gid < NBv)
      atomicAdd(&bias[bidx[gid]], bv[gid]);
    return;
  }

  // ---- build_h branch ----
  const int b = blockIdx.x;
  const float* xr = x + (size_t)b * F0v;
  unsigned short* hr = h + (size_t)b * F2v;

  // tail-resolution table (identical per block; cheap recompute)
  {
    tsrc[tid] = e1p[tid]; twa[tid] = e1w[tid]; twb[tid] = 1.0f;
    int p2 = e2p[tid]; float w2 = e2w[tid];
    if (p2 < F0v) {
      tsrc[E1v + tid] = p2;  twa[E1v + tid] = w2;  twb[E1v + tid] = 1.0f;
    } else {
      int q = p2 - F0v;
      tsrc[E1v + tid] = e1p[q]; twa[E1v + tid] = e1w[q]; twb[E1v + tid] = w2;
    }
  }

  float4 v0 = ((const float4*)xr)[tid * 2];
  float4 v1 = ((const float4*)xr)[tid * 2 + 1];
  ((float4*)xrow)[tid * 2] = v0;
  ((float4*)xrow)[tid * 2 + 1] = v1;
  union { unsigned short us[8]; uint4 u4; } pk;
  pk.us[0] = f2bf(v0.x); pk.us[1] = f2bf(v0.y);
  pk.us[2] = f2bf(v0.z); pk.us[3] = f2bf(v0.w);
  pk.us[4] = f2bf(v1.x); pk.us[5] = f2bf(v1.y);
  pk.us[6] = f2bf(v1.z); pk.us[7] = f2bf(v1.w);
  ((uint4*)hr)[tid] = pk.u4;   // cols tid*8 .. tid*8+7
  __syncthreads();

  // two tail cols per thread: 2048+2*tid, 2049+2*tid
  int j0 = tid * 2;
  float a0 = fmaxf(fmaxf(xrow[tsrc[j0]] * twa[j0], 0.0f) * twb[j0], 0.0f);
  float a1 = fmaxf(fmaxf(xrow[tsrc[j0 + 1]] * twa[j0 + 1], 0.0f) * twb[j0 + 1], 0.0f);
  unsigned int packed = (unsigned int)f2bf(a0) | ((unsigned int)f2bf(a1) << 16);
  ((unsigned int*)(hr + F0v))[tid] = packed;
}

// ---------------------------------------------------------------------------
// Kernel 2: W f32 -> bf16 (8 elems/thread)
// ---------------------------------------------------------------------------
__global__ __launch_bounds__(256) void convert_kernel(
    const float* __restrict__ Wd, unsigned short* __restrict__ Wb) {
  int gid = blockIdx.x * 256 + threadIdx.x;  // 0 .. 327679
  const float4* src = (const float4*)Wd;
  float4 a = src[gid * 2];
  float4 b = src[gid * 2 + 1];
  union { unsigned short us[8]; uint4 u4; } pk;
  pk.us[0] = f2bf(a.x); pk.us[1] = f2bf(a.y);
  pk.us[2] = f2bf(a.z); pk.us[3] = f2bf(a.w);
  pk.us[4] = f2bf(b.x); pk.us[5] = f2bf(b.y);
  pk.us[6] = f2bf(b.z); pk.us[7] = f2bf(b.w);
  ((uint4*)Wb)[gid] = pk.u4;
}

// ---------------------------------------------------------------------------
// Kernel 3: C = h @ W^T + bias.  128x128 tile, BK=64, double-buffered LDS,
// 512 threads (8 waves), acc[4][2] of 16x16x32 bf16 MFMA per wave.
// XOR swizzle (seg ^ (row&7)) on 16B k-segments kills the 128B-stride
// bank conflicts; swizzle applied in the staging lane->global map, so
// coalescing is unchanged (segs within a row are permuted).
// ---------------------------------------------------------------------------
#define BM 128
#define BN 128
#define BK 64

__global__ __launch_bounds__(512) void gemm_bt_kernel(
    const unsigned short* __restrict__ A,
    const unsigned short* __restrict__ Bw,
    const float* __restrict__ bias,
    float* __restrict__ C) {
  __shared__ unsigned short As[2][BM * BK];   // 2 x 16 KB
  __shared__ unsigned short Bs[2][BN * BK];   // 2 x 16 KB
  const int tid = threadIdx.x;
  const int wave = tid >> 6;      // 0..7
  const int lane = tid & 63;

  // XCD swizzle: grid (8, 64); id%8 = XCD. XCD k owns M-tiles [8k,8k+8).
  const int id = blockIdx.y * 8 + blockIdx.x;
  const int ty = (id & 7) * 8 + ((id >> 3) & 7);   // M-tile 0..63
  const int tx = id >> 6;                          // N-tile 0..7
  const int m0 = ty * BM;
  const int n0 = tx * BN;
  const int wm = wave >> 2;       // 0..1  (64-row half)
  const int wn = wave & 3;        // 0..3  (32-col quarter)
  const int quad = lane >> 4;     // 0..3
  const int r16 = lane & 15;

  // Staging: chunk = 8 rows x 64 cols (1 KiB). A/B each 16 chunks; wave w
  // stages chunks {2w, 2w+1} of both. Lane L covers row L/8, stored seg L%8,
  // sourcing global seg (L%8)^((L/8)&7)  [the XOR swizzle].
  const int c0 = wave * 2;
  const int lrow = lane >> 3;                 // 0..7 within chunk
  const int gseg = ((lane & 7) ^ (lrow & 7)); // swizzled global 16B segment
  const unsigned short* gA0 = A + (size_t)(m0 + c0 * 8 + lrow) * F2v + gseg * 8;
  const unsigned short* gA1 = A + (size_t)(m0 + (c0 + 1) * 8 + lrow) * F2v + gseg * 8;
  const unsigned short* gB0 = Bw + (size_t)(n0 + c0 * 8 + lrow) * F2v + gseg * 8;
  const unsigned short* gB1 = Bw + (size_t)(n0 + (c0 + 1) * 8 + lrow) * F2v + gseg * 8;
  const int lA0 = c0 * 512, lA1 = (c0 + 1) * 512;

  floatx4 acc[4][2];
  floatx4 zz = {0.f, 0.f, 0.f, 0.f};
#pragma unroll
  for (int i = 0; i < 4; ++i)
#pragma unroll
    for (int j = 0; j < 2; ++j) acc[i][j] = zz;

  // prologue: stage k-block 0 into buffer 0
  async_ld16(gA0, &As[0][lA0]);
  async_ld16(gA1, &As[0][lA1]);
  async_ld16(gB0, &Bs[0][lA0]);
  async_ld16(gB1, &Bs[0][lA1]);

  for (int k0 = 0; k0 < F2v; k0 += BK) {
    const int pb = (k0 >> 6) & 1;
    __syncthreads();   // drains this buffer's loads; frees other buffer
    if (k0 + BK < F2v) {
      const int nb = pb ^ 1;
      async_ld16(gA0 + k0 + BK, &As[nb][lA0]);
      async_ld16(gA1 + k0 + BK, &As[nb][lA1]);
      async_ld16(gB0 + k0 + BK, &Bs[nb][lA0]);
      async_ld16(gB1 + k0 + BK, &Bs[nb][lA1]);
    }

    // fragment reads (swizzled): element (row, seg) at row*64 + (seg^(row&7))*8
#pragma unroll
    for (int kk = 0; kk < 2; ++kk) {
      bf16x8 af[4], bfr[2];
#pragma unroll
      for (int mi = 0; mi < 4; ++mi) {
        int row = wm * 64 + mi * 16 + r16;
        af[mi] = *(const bf16x8*)&As[pb][row * BK + (((kk * 4 + quad) ^ (r16 & 7)) * 8)];
      }
#pragma unroll
      for (int ni = 0; ni < 2; ++ni) {
        int row = wn * 32 + ni * 16 + r16;
        bfr[ni] = *(const bf16x8*)&Bs[pb][row * BK + (((kk * 4 + quad) ^ (r16 & 7)) * 8)];
      }
#pragma unroll
      for (int mi = 0; mi < 4; ++mi)
#pragma unroll
        for (int ni = 0; ni < 2; ++ni)
          acc[mi][ni] = __builtin_amdgcn_mfma_f32_16x16x32_bf16(
              af[mi], bfr[ni], acc[mi][ni], 0, 0, 0);
    }
  }

  // Epilogue: C/D layout col = lane&15, row = quad*4 + reg (m89/m91 verified)
#pragma unroll
  for (int ni = 0; ni < 2; ++ni) {
    int col = n0 + wn * 32 + ni * 16 + r16;
    float bc = bias[col];
#pragma unroll
    for (int mi = 0; mi < 4; ++mi) {
      int row = m0 + wm * 64 + mi * 16 + quad * 4;
#pragma unroll
      for (int rg = 0; rg < 4; ++rg)
        C[(size_t)(row + rg) * ODIM + col] = acc[mi][ni][rg] + bc;
    }
  }
}

// ---------------------------------------------------------------------------
extern "C" void kernel_launch(void* const* d_in, const int* in_sizes, int n_in,
                              void* d_out, int out_size, void* d_ws, size_t ws_size,
                              hipStream_t stream) {
  const float* x    = (const float*)d_in[0];
  const float* e1w  = (const float*)d_in[1];
  const float* e2w  = (const float*)d_in[2];
  const float* wv   = (const float*)d_in[3];
  const float* bv   = (const float*)d_in[4];
  const int*   e1p  = (const int*)d_in[5];
  const int*   e2p  = (const int*)d_in[6];
  const int*   wr   = (const int*)d_in[7];
  const int*   wc   = (const int*)d_in[8];
  const int*   bidx = (const int*)d_in[9];
  float* out = (float*)d_out;

  // Workspace carve (total ~57.7 MB)
  char* ws = (char*)d_ws;
  const size_t h_bytes  = (size_t)BROWS * F2v * 2;        // 41,943,040
  const size_t wd_bytes = (size_t)ODIM * F2v * 4;         // 10,485,760
  const size_t b_bytes  = (size_t)ODIM * 4;               // 4,096
  unsigned short* h   = (unsigned short*)ws;
  float* Wd           = (float*)(ws + h_bytes);
  float* bias         = (float*)(ws + h_bytes + wd_bytes);
  unsigned short* Wb  = (unsigned short*)(ws + h_bytes + wd_bytes + b_bytes);

  hipMemsetAsync(Wd, 0, wd_bytes + b_bytes, stream);
  fused_pre_kernel<<<BROWS + NNZv / 256, 256, 0, stream>>>(
      x, e1w, e2w, e1p, e2p, h, wr, wc, wv, bidx, bv, Wd, bias);
  convert_kernel<<<(ODIM * F2v / 8) / 256, 256, 0, stream>>>(Wd, Wb);
  gemm_bt_kernel<<<dim3(ODIM / BN, BROWS / BM), 512, 0, stream>>>(h, Wb, bias, out);
}